// Round 11
// baseline (145.161 us; speedup 1.0000x reference)
//
#include <hip/hip_runtime.h>
#include <hip/hip_bf16.h>
#include <math.h>

typedef __bf16 bf16x8 __attribute__((ext_vector_type(8)));
typedef float  f32x4  __attribute__((ext_vector_type(4)));

#define NND 8192
#define DIM 64
#define SLOT  1024          // floats per tile slot (16 rows x 64 cols)
#define WSLAB 3072          // floats per wave slab (3 slots, depth-3 pipeline)

typedef const __attribute__((address_space(1))) void* gaddr_t;
typedef __attribute__((address_space(3))) void* laddr_t;

__device__ __forceinline__ float wsum(float v) {
#pragma unroll
    for (int m = 1; m < 64; m <<= 1) v += __shfl_xor(v, m, 64);
    return v;
}

struct SC { float sh, ch; };
__device__ __forceinline__ SC sinhcosh(float c) {
    float e  = expf(c);
    float ei = 1.0f / e;
    SC r; r.sh = 0.5f * (e - ei); r.ch = 0.5f * (e + ei);
    return r;
}

__device__ __forceinline__ float arcosh_from_n2(float n2) {
    float t = fmaxf(n2, 2.0000001e-7f);
    return logf(sqrtf(1.0f + t) + sqrtf(t));
}

__device__ __forceinline__ float tangent_chain(float xv, int lane) {
    float y   = (lane == 0) ? 0.0f : xv;
    float yn2 = wsum(y * y);
    float yn  = fmaxf(sqrtf(fmaxf(yn2, 1e-30f)), 1e-15f);
    SC s1 = sinhcosh(fminf(yn, 15.0f));
    float r   = (lane == 0) ? 0.0f : s1.sh * y / yn;
    float rn2 = wsum(r * r);
    float ynb = fmaxf(sqrtf(fmaxf(rn2, 1e-30f)), 1e-15f);
    float ac  = arcosh_from_n2(rn2);
    return (lane == 0) ? 0.0f : ac * r / ynb;
}

__device__ __forceinline__ float second_chain(float m, float ubv, float theta_b, int lane) {
    float my  = (lane == 0) ? 0.0f : m;
    float mn2 = wsum(my * my);
    float mn  = fmaxf(sqrtf(fmaxf(mn2, 1e-30f)), 1e-15f);
    SC s2 = sinhcosh(fminf(mn, 15.0f));
    float rr   = (lane == 0) ? 0.0f : s2.sh * my / mn;
    float rrn2 = wsum(rr * rr);
    float res0 = sqrtf(fmaxf(1.0f + rrn2, 1e-7f));
    float yn3   = fmaxf(sqrtf(fmaxf(rrn2, 1e-30f)), 1e-15f);
    float yhat  = (lane == 0) ? 0.0f : rr / yn3;
    float alpha = wsum(yhat * ubv);
    float w_    = ubv - alpha * (1.0f - res0) * yhat;
    float ux    = wsum(rr * w_);
    float v0    = ux / fmaxf(res0, 1e-7f);
    float vv    = (lane == 0) ? v0 : w_;
    float resv  = (lane == 0) ? res0 : rr;
    float theta = theta_b;
    SC s3 = sinhcosh(fminf(theta, 15.0f));
    float pv  = s3.ch * resv + s3.sh * vv / theta;
    float pn2 = wsum((lane == 0) ? 0.0f : pv * pv);
    float yn4 = fmaxf(sqrtf(fmaxf(pn2, 1e-30f)), 1e-15f);
    float ac4 = arcosh_from_n2(pn2);
    return (lane == 0) ? 0.0f : ac4 * pv / yn4;
}

__device__ __forceinline__ float epilogue_chain(float hv, int lane) {
    float y   = (lane == 0) ? 0.0f : hv;
    float yn2 = wsum(y * y);
    float yn  = fmaxf(sqrtf(fmaxf(yn2, 1e-30f)), 1e-15f);
    SC s1 = sinhcosh(fminf(yn, 15.0f));
    float r   = (lane == 0) ? 0.0f : s1.sh * y / yn;
    float rn2 = wsum(r * r);
    float ynb = fmaxf(sqrtf(fmaxf(rn2, 1e-30f)), 1e-15f);
    float ac  = arcosh_from_n2(rn2);
    float lgv = (lane == 0) ? 0.0f : ac * r / ynb;
    float t   = (lgv > 0.0f) ? lgv : 0.01f * lgv;
    float tn2 = wsum(t * t);
    float tn  = fmaxf(sqrtf(fmaxf(tn2, 1e-30f)), 1e-15f);
    SC s3 = sinhcosh(fminf(tn, 15.0f));
    float ov  = (lane == 0) ? 0.0f : s3.sh * t / tn;
    float on2 = wsum(ov * ov);
    float o0  = sqrtf(fmaxf(1.0f + on2, 1e-7f));
    return (lane == 0) ? o0 : ov;
}

// PROBE: pure-stream read of adj, 3 passes (768 MB demand), max-favorable shape:
// 2048x256, float4/lane, 32 fully-unrolled independent loads per pass. Measures
// the platform's sustained pure-READ bandwidth. Sink write prevents DCE.
__global__ __launch_bounds__(256) void k_probe(
    const f32x4* __restrict__ adj4, float* __restrict__ sink)
{
    const int tid    = blockIdx.x * 256 + threadIdx.x;
    const int stride = 2048 * 256;
    f32x4 a0 = {0.f, 0.f, 0.f, 0.f};
    f32x4 a1 = a0, a2 = a0, a3 = a0;
    for (int p = 0; p < 3; ++p) {
#pragma unroll
        for (int i = 0; i < 32; i += 4) {
            a0 += adj4[(size_t)(i + 0) * stride + tid];
            a1 += adj4[(size_t)(i + 1) * stride + tid];
            a2 += adj4[(size_t)(i + 2) * stride + tid];
            a3 += adj4[(size_t)(i + 3) * stride + tid];
        }
    }
    f32x4 s = (a0 + a1) + (a2 + a3);
    sink[tid] = s[0] + s[1] + s[2] + s[3];
}

// Kernel 1: per-row chain + 64x64 matvec; 1 row per wave. (round-7 verbatim)
__global__ __launch_bounds__(256) void k_prep(
    const float* __restrict__ x, const float* __restrict__ weight,
    const float* __restrict__ bias, __bf16* __restrict__ l2bfT)
{
    __shared__ float WL[64][65];
    const int tid  = threadIdx.x;
    const int lane = tid & 63;
    const int wave = tid >> 6;
#pragma unroll
    for (int i = 0; i < 16; ++i) {
        int idx = i * 256 + tid;
        WL[idx >> 6][idx & 63] = weight[idx];
    }
    __syncthreads();
    float ubv  = tangent_chain(bias[lane], lane);
    float nub2 = wsum(ubv * ubv);
    float thb  = fmaxf(fminf(sqrtf(fmaxf(nub2, 1e-7f)), 1e6f), 1e-15f);

    const int row = blockIdx.x * 4 + wave;
    float xv  = x[row * 64 + lane];
    float L1v = tangent_chain(xv, lane);
    float mj0 = 0.f, mj1 = 0.f, mj2 = 0.f, mj3 = 0.f;
#pragma unroll
    for (int d = 0; d < 64; d += 4) {
        mj0 = fmaf(__shfl(L1v, d,     64), WL[lane][d],     mj0);
        mj1 = fmaf(__shfl(L1v, d + 1, 64), WL[lane][d + 1], mj1);
        mj2 = fmaf(__shfl(L1v, d + 2, 64), WL[lane][d + 2], mj2);
        mj3 = fmaf(__shfl(L1v, d + 3, 64), WL[lane][d + 3], mj3);
    }
    float mj  = (mj0 + mj1) + (mj2 + mj3);
    float L2v = second_chain(mj, ubv, thb, lane);
    l2bfT[(size_t)lane * NND + row] = (__bf16)L2v;
}

#define DMA_TILE(T) do {                                                        \
    _Pragma("unroll")                                                           \
    for (int g_ = 0; g_ < 4; ++g_) {                                            \
        int row_ = 4 * g_ + (lane >> 4);                                        \
        int cs_  = (lane & 15) ^ (row_ & 7);                                    \
        const float* gp_ = adj + (size_t)(R0 + row_) * NND + kw + (T) * 64 + 4 * cs_; \
        float* lp_ = myslab + ((T) % 3) * SLOT + g_ * 256;                      \
        __builtin_amdgcn_global_load_lds((gaddr_t)gp_, (laddr_t)lp_, 16, 0, 0); \
    }                                                                           \
} while (0)

#define KITER(T, PF, WSTR) do {                                                 \
    asm volatile(WSTR ::: "memory");                                            \
    __builtin_amdgcn_sched_barrier(0);                                          \
    const float* Ar_ = myslab + ((T) % 3) * SLOT + l15 * 64;                    \
    f32x4 a00 = *reinterpret_cast<const f32x4*>(Ar_ + (((2*lg    ) ^ rx) << 2));\
    f32x4 a01 = *reinterpret_cast<const f32x4*>(Ar_ + (((2*lg + 1) ^ rx) << 2));\
    f32x4 a10 = *reinterpret_cast<const f32x4*>(Ar_ + (((2*lg + 8) ^ rx) << 2));\
    f32x4 a11 = *reinterpret_cast<const f32x4*>(Ar_ + (((2*lg + 9) ^ rx) << 2));\
    const int kq_ = (T) * 64;                                                   \
    bf16x8 b00 = *reinterpret_cast<const bf16x8*>(bp0 + kq_);                   \
    bf16x8 b10 = *reinterpret_cast<const bf16x8*>(bp1 + kq_);                   \
    bf16x8 b20 = *reinterpret_cast<const bf16x8*>(bp2 + kq_);                   \
    bf16x8 b30 = *reinterpret_cast<const bf16x8*>(bp3 + kq_);                   \
    bf16x8 b01 = *reinterpret_cast<const bf16x8*>(bp0 + kq_ + 32);              \
    bf16x8 b11 = *reinterpret_cast<const bf16x8*>(bp1 + kq_ + 32);              \
    bf16x8 b21 = *reinterpret_cast<const bf16x8*>(bp2 + kq_ + 32);              \
    bf16x8 b31 = *reinterpret_cast<const bf16x8*>(bp3 + kq_ + 32);              \
    asm volatile("" ::: "memory");                                              \
    if (PF) { DMA_TILE((T) + 3); }                                              \
    bf16x8 av0, av1;                                                            \
    av0[0]=(__bf16)a00[0]; av0[1]=(__bf16)a00[1]; av0[2]=(__bf16)a00[2]; av0[3]=(__bf16)a00[3]; \
    av0[4]=(__bf16)a01[0]; av0[5]=(__bf16)a01[1]; av0[6]=(__bf16)a01[2]; av0[7]=(__bf16)a01[3]; \
    av1[0]=(__bf16)a10[0]; av1[1]=(__bf16)a10[1]; av1[2]=(__bf16)a10[2]; av1[3]=(__bf16)a10[3]; \
    av1[4]=(__bf16)a11[0]; av1[5]=(__bf16)a11[1]; av1[6]=(__bf16)a11[2]; av1[7]=(__bf16)a11[3]; \
    acc0 = __builtin_amdgcn_mfma_f32_16x16x32_bf16(av0, b00, acc0, 0, 0, 0);    \
    acc1 = __builtin_amdgcn_mfma_f32_16x16x32_bf16(av0, b10, acc1, 0, 0, 0);    \
    acc2 = __builtin_amdgcn_mfma_f32_16x16x32_bf16(av0, b20, acc2, 0, 0, 0);    \
    acc3 = __builtin_amdgcn_mfma_f32_16x16x32_bf16(av0, b30, acc3, 0, 0, 0);    \
    acc0 = __builtin_amdgcn_mfma_f32_16x16x32_bf16(av1, b01, acc0, 0, 0, 0);    \
    acc1 = __builtin_amdgcn_mfma_f32_16x16x32_bf16(av1, b11, acc1, 0, 0, 0);    \
    acc2 = __builtin_amdgcn_mfma_f32_16x16x32_bf16(av1, b21, acc2, 0, 0, 0);    \
    acc3 = __builtin_amdgcn_mfma_f32_16x16x32_bf16(av1, b31, acc3, 0, 0, 0);    \
} while (0)

// Kernel 2: round-7 verbatim (fastest passing: 2048 blocks, wave-private
// depth-3 DMA pipeline, no barrier in K-loop).
__global__ __launch_bounds__(256, 3) void k_mm(
    const float* __restrict__ adj, const __bf16* __restrict__ l2bfT,
    float* __restrict__ pws)
{
    __shared__ float slab[4 * WSLAB];
    const int tid  = threadIdx.x;
    const int lane = tid & 63;
    const int w    = tid >> 6;
    const int l15  = lane & 15;
    const int lg   = lane >> 4;
    const int rx   = l15 & 7;
    const int rb   = blockIdx.x >> 2;        // row-group (0..511)
    const int h    = blockIdx.x & 3;         // k-quarter
    const int R0   = rb * 16;
    const int kw   = h * 2048 + w * 512;

    float* const myslab = slab + w * WSLAB;

    const __bf16* bp0 = l2bfT + (size_t)(l15)      * NND + kw + 8 * lg;
    const __bf16* bp1 = l2bfT + (size_t)(16 + l15) * NND + kw + 8 * lg;
    const __bf16* bp2 = l2bfT + (size_t)(32 + l15) * NND + kw + 8 * lg;
    const __bf16* bp3 = l2bfT + (size_t)(48 + l15) * NND + kw + 8 * lg;

    f32x4 acc0 = {0.f, 0.f, 0.f, 0.f};
    f32x4 acc1 = acc0, acc2 = acc0, acc3 = acc0;

    DMA_TILE(0); DMA_TILE(1); DMA_TILE(2);

    KITER(0, true,  "s_waitcnt vmcnt(8)");
    KITER(1, true,  "s_waitcnt vmcnt(16)");
    KITER(2, true,  "s_waitcnt vmcnt(24)");
    KITER(3, true,  "s_waitcnt vmcnt(24)");
    KITER(4, true,  "s_waitcnt vmcnt(24)");
    KITER(5, false, "s_waitcnt vmcnt(24)");
    KITER(6, false, "s_waitcnt vmcnt(20)");
    KITER(7, false, "s_waitcnt vmcnt(16)");

    __syncthreads();
    float (*Ct)[16][65] = reinterpret_cast<float (*)[16][65]>(slab);
#pragma unroll
    for (int i = 0; i < 4; ++i) {
        Ct[w][lg * 4 + i][ 0 + l15] = acc0[i];
        Ct[w][lg * 4 + i][16 + l15] = acc1[i];
        Ct[w][lg * 4 + i][32 + l15] = acc2[i];
        Ct[w][lg * 4 + i][48 + l15] = acc3[i];
    }
    __syncthreads();

    float* pp = pws + (size_t)h * NND * DIM;
#pragma unroll
    for (int i = 0; i < 4; ++i) {
        int r = w * 4 + i;
        float hv = (Ct[0][r][lane] + Ct[1][r][lane])
                 + (Ct[2][r][lane] + Ct[3][r][lane]);
        pp[(size_t)(R0 + r) * DIM + lane] = hv;
    }
}

// Kernel 3: sum 4 k-quarter partials + fused epilogue. (round-7 verbatim)
__global__ __launch_bounds__(256) void k_fin(
    const float* __restrict__ pws, float* __restrict__ out)
{
    const int tid  = threadIdx.x;
    const int lane = tid & 63;
    const int wave = tid >> 6;
    const int row  = blockIdx.x * 4 + wave;
    const size_t base = (size_t)row * DIM + lane;
    float hv = (pws[base] + pws[(size_t)NND * DIM + base])
             + (pws[2 * (size_t)NND * DIM + base] + pws[3 * (size_t)NND * DIM + base]);
    out[base] = epilogue_chain(hv, lane);
}

extern "C" void kernel_launch(void* const* d_in, const int* in_sizes, int n_in,
                              void* d_out, int out_size, void* d_ws, size_t ws_size,
                              hipStream_t stream)
{
    const float* x      = (const float*)d_in[0];
    const float* adj    = (const float*)d_in[1];
    const float* weight = (const float*)d_in[2];
    const float* bias   = (const float*)d_in[3];
    float* out = (float*)d_out;
    __bf16* l2bfT = (__bf16*)d_ws;                                   // 1 MB
    float*  pws   = (float*)((char*)d_ws + (1 << 20));               // 8 MB partials
    float*  sink  = (float*)((char*)d_ws + (1 << 20) + 8 * (1 << 20)); // 2 MB probe sink

    k_probe<<<2048, 256, 0, stream>>>((const f32x4*)adj, sink);      // read-BW probe
    k_prep<<<2048, 256, 0, stream>>>(x, weight, bias, l2bfT);
    k_mm<<<2048, 256, 0, stream>>>(adj, l2bfT, pws);
    k_fin<<<2048, 256, 0, stream>>>(pws, out);
}

// Round 12
// 94.805 us; speedup vs baseline: 1.5311x; 1.5311x over previous
//
#include <hip/hip_runtime.h>
#include <hip/hip_bf16.h>
#include <math.h>

typedef __bf16 bf16x8 __attribute__((ext_vector_type(8)));
typedef float  f32x4  __attribute__((ext_vector_type(4)));

#define NND 8192
#define DIM 64
#define PB  10368   // l2bf padded row stride in bf16: 20736 B = 81*256B (odd multiple
                    // of 256B) -> 16-lane row-scatter spreads across L2/L3 channels

__device__ __forceinline__ float wsum(float v) {
#pragma unroll
    for (int m = 1; m < 64; m <<= 1) v += __shfl_xor(v, m, 64);
    return v;
}

struct SC { float sh, ch; };
__device__ __forceinline__ SC sinhcosh(float c) {
    float e  = expf(c);
    float ei = 1.0f / e;
    SC r; r.sh = 0.5f * (e - ei); r.ch = 0.5f * (e + ei);
    return r;
}

__device__ __forceinline__ float arcosh_from_n2(float n2) {
    float t = fmaxf(n2, 2.0000001e-7f);
    return logf(sqrtf(1.0f + t) + sqrtf(t));
}

__device__ __forceinline__ float tangent_chain(float xv, int lane) {
    float y   = (lane == 0) ? 0.0f : xv;
    float yn2 = wsum(y * y);
    float yn  = fmaxf(sqrtf(fmaxf(yn2, 1e-30f)), 1e-15f);
    SC s1 = sinhcosh(fminf(yn, 15.0f));
    float r   = (lane == 0) ? 0.0f : s1.sh * y / yn;
    float rn2 = wsum(r * r);
    float ynb = fmaxf(sqrtf(fmaxf(rn2, 1e-30f)), 1e-15f);
    float ac  = arcosh_from_n2(rn2);
    return (lane == 0) ? 0.0f : ac * r / ynb;
}

__device__ __forceinline__ float second_chain(float m, float ubv, float theta_b, int lane) {
    float my  = (lane == 0) ? 0.0f : m;
    float mn2 = wsum(my * my);
    float mn  = fmaxf(sqrtf(fmaxf(mn2, 1e-30f)), 1e-15f);
    SC s2 = sinhcosh(fminf(mn, 15.0f));
    float rr   = (lane == 0) ? 0.0f : s2.sh * my / mn;
    float rrn2 = wsum(rr * rr);
    float res0 = sqrtf(fmaxf(1.0f + rrn2, 1e-7f));
    float yn3   = fmaxf(sqrtf(fmaxf(rrn2, 1e-30f)), 1e-15f);
    float yhat  = (lane == 0) ? 0.0f : rr / yn3;
    float alpha = wsum(yhat * ubv);
    float w_    = ubv - alpha * (1.0f - res0) * yhat;
    float ux    = wsum(rr * w_);
    float v0    = ux / fmaxf(res0, 1e-7f);
    float vv    = (lane == 0) ? v0 : w_;
    float resv  = (lane == 0) ? res0 : rr;
    float theta = theta_b;
    SC s3 = sinhcosh(fminf(theta, 15.0f));
    float pv  = s3.ch * resv + s3.sh * vv / theta;
    float pn2 = wsum((lane == 0) ? 0.0f : pv * pv);
    float yn4 = fmaxf(sqrtf(fmaxf(pn2, 1e-30f)), 1e-15f);
    float ac4 = arcosh_from_n2(pn2);
    return (lane == 0) ? 0.0f : ac4 * pv / yn4;
}

__device__ __forceinline__ float epilogue_chain(float hv, int lane) {
    float y   = (lane == 0) ? 0.0f : hv;
    float yn2 = wsum(y * y);
    float yn  = fmaxf(sqrtf(fmaxf(yn2, 1e-30f)), 1e-15f);
    SC s1 = sinhcosh(fminf(yn, 15.0f));
    float r   = (lane == 0) ? 0.0f : s1.sh * y / yn;
    float rn2 = wsum(r * r);
    float ynb = fmaxf(sqrtf(fmaxf(rn2, 1e-30f)), 1e-15f);
    float ac  = arcosh_from_n2(rn2);
    float lgv = (lane == 0) ? 0.0f : ac * r / ynb;
    float t   = (lgv > 0.0f) ? lgv : 0.01f * lgv;
    float tn2 = wsum(t * t);
    float tn  = fmaxf(sqrtf(fmaxf(tn2, 1e-30f)), 1e-15f);
    SC s3 = sinhcosh(fminf(tn, 15.0f));
    float ov  = (lane == 0) ? 0.0f : s3.sh * t / tn;
    float on2 = wsum(ov * ov);
    float o0  = sqrtf(fmaxf(1.0f + on2, 1e-7f));
    return (lane == 0) ? o0 : ov;
}

// Kernel 1: per-row chain + 64x64 matvec; 1 row per wave. Only change: padded
// l2bf row stride (PB).
__global__ __launch_bounds__(256) void k_prep(
    const float* __restrict__ x, const float* __restrict__ weight,
    const float* __restrict__ bias, __bf16* __restrict__ l2bf)
{
    __shared__ float WL[64][65];
    const int tid  = threadIdx.x;
    const int lane = tid & 63;
    const int wave = tid >> 6;
#pragma unroll
    for (int i = 0; i < 16; ++i) {
        int idx = i * 256 + tid;
        WL[idx >> 6][idx & 63] = weight[idx];
    }
    __syncthreads();
    float ubv  = tangent_chain(bias[lane], lane);
    float nub2 = wsum(ubv * ubv);
    float thb  = fmaxf(fminf(sqrtf(fmaxf(nub2, 1e-7f)), 1e6f), 1e-15f);

    const int row = blockIdx.x * 4 + wave;
    float xv  = x[row * 64 + lane];
    float L1v = tangent_chain(xv, lane);
    float mj0 = 0.f, mj1 = 0.f, mj2 = 0.f, mj3 = 0.f;
#pragma unroll
    for (int d = 0; d < 64; d += 4) {
        mj0 = fmaf(__shfl(L1v, d,     64), WL[lane][d],     mj0);
        mj1 = fmaf(__shfl(L1v, d + 1, 64), WL[lane][d + 1], mj1);
        mj2 = fmaf(__shfl(L1v, d + 2, 64), WL[lane][d + 2], mj2);
        mj3 = fmaf(__shfl(L1v, d + 3, 64), WL[lane][d + 3], mj3);
    }
    float mj  = (mj0 + mj1) + (mj2 + mj3);
    float L2v = second_chain(mj, ubv, thb, lane);
    l2bf[(size_t)lane * PB + row] = (__bf16)L2v;
}

// Kernel 2: partial h_tan = adj[R0:R0+32, quarter] @ L2^T.
// 1024 blocks = 256 row-groups (32 rows) x 4 k-quarters (2048 k).
// Waves own d-blocks (16 dims each) and sweep the full quarter -> no cross-wave
// k-reduction. A staged via contiguous 512B bursts (reg->LDS dbuf); B fragments
// direct from channel-despread padded l2bf. Camping-free by construction.
__global__ __launch_bounds__(256, 4) void k_mm(
    const float* __restrict__ adj, const __bf16* __restrict__ l2bf,
    float* __restrict__ pws)
{
    __shared__ float AL[2][32][132];         // 33792 B, row stride 132 (bank-spread)
    const int tid  = threadIdx.x;
    const int lane = tid & 63;
    const int w    = tid >> 6;               // wave = d-block owner (dims 16w..16w+15)
    const int l15  = lane & 15;
    const int lg   = lane >> 4;
    const int h    = blockIdx.x & 3;         // k-quarter
    const int rb   = blockIdx.x >> 2;        // row-group
    const int R0   = rb * 32;
    const int kq   = h * 2048;

    const int srow = tid >> 5;               // 0..7 (staging row within 8-row band)
    const int scol = (tid & 31) * 4;         // 0..124 (staging col, floats)

    // B base: dim row (16w + l15), padded stride PB -> channel-spread scatter
    const __bf16* bp = l2bf + (size_t)(16 * w + l15) * PB + kq + 8 * lg;

    f32x4 accL = {0.f, 0.f, 0.f, 0.f};      // rows R0..R0+15 of this d-block
    f32x4 accH = accL;                       // rows R0+16..R0+31

    // ---- prologue: stage tile 0 (32 rows x 128 floats) into AL[0]
    {
        const float* g = adj + (size_t)(R0 + srow) * NND + kq + scol;
        f32x4 s0 = *reinterpret_cast<const f32x4*>(g);
        f32x4 s1 = *reinterpret_cast<const f32x4*>(g + (size_t)8  * NND);
        f32x4 s2 = *reinterpret_cast<const f32x4*>(g + (size_t)16 * NND);
        f32x4 s3 = *reinterpret_cast<const f32x4*>(g + (size_t)24 * NND);
        *reinterpret_cast<f32x4*>(&AL[0][srow     ][scol]) = s0;
        *reinterpret_cast<f32x4*>(&AL[0][srow +  8][scol]) = s1;
        *reinterpret_cast<f32x4*>(&AL[0][srow + 16][scol]) = s2;
        *reinterpret_cast<f32x4*>(&AL[0][srow + 24][scol]) = s3;
    }
    __syncthreads();

    for (int t = 0; t < 16; ++t) {
        const int cur = t & 1;
        f32x4 s0, s1, s2, s3;
        const bool pf = (t < 15);
        if (pf) {                            // issue next-tile loads EARLY (contiguous)
            const float* g = adj + (size_t)(R0 + srow) * NND + kq + (t + 1) * 128 + scol;
            s0 = *reinterpret_cast<const f32x4*>(g);
            s1 = *reinterpret_cast<const f32x4*>(g + (size_t)8  * NND);
            s2 = *reinterpret_cast<const f32x4*>(g + (size_t)16 * NND);
            s3 = *reinterpret_cast<const f32x4*>(g + (size_t)24 * NND);
        }
        // consume tile t: 4 k-steps of 32
#pragma unroll
        for (int ks = 0; ks < 4; ++ks) {
            const int kk = t * 128 + ks * 32;                 // within quarter
            bf16x8 b = *reinterpret_cast<const bf16x8*>(bp + kk);
            const float* arL = &AL[cur][l15     ][ks * 32 + 8 * lg];
            const float* arH = &AL[cur][16 + l15][ks * 32 + 8 * lg];
            f32x4 a0 = *reinterpret_cast<const f32x4*>(arL);
            f32x4 a1 = *reinterpret_cast<const f32x4*>(arL + 4);
            f32x4 c0 = *reinterpret_cast<const f32x4*>(arH);
            f32x4 c1 = *reinterpret_cast<const f32x4*>(arH + 4);
            bf16x8 avL, avH;
            avL[0] = (__bf16)a0[0]; avL[1] = (__bf16)a0[1];
            avL[2] = (__bf16)a0[2]; avL[3] = (__bf16)a0[3];
            avL[4] = (__bf16)a1[0]; avL[5] = (__bf16)a1[1];
            avL[6] = (__bf16)a1[2]; avL[7] = (__bf16)a1[3];
            avH[0] = (__bf16)c0[0]; avH[1] = (__bf16)c0[1];
            avH[2] = (__bf16)c0[2]; avH[3] = (__bf16)c0[3];
            avH[4] = (__bf16)c1[0]; avH[5] = (__bf16)c1[1];
            avH[6] = (__bf16)c1[2]; avH[7] = (__bf16)c1[3];
            accL = __builtin_amdgcn_mfma_f32_16x16x32_bf16(avL, b, accL, 0, 0, 0);
            accH = __builtin_amdgcn_mfma_f32_16x16x32_bf16(avH, b, accH, 0, 0, 0);
        }
        __syncthreads();                     // all waves done reading AL[cur^1] (and cur)
        if (pf) {                            // write staged regs LATE into other buffer
            *reinterpret_cast<f32x4*>(&AL[cur ^ 1][srow     ][scol]) = s0;
            *reinterpret_cast<f32x4*>(&AL[cur ^ 1][srow +  8][scol]) = s1;
            *reinterpret_cast<f32x4*>(&AL[cur ^ 1][srow + 16][scol]) = s2;
            *reinterpret_cast<f32x4*>(&AL[cur ^ 1][srow + 24][scol]) = s3;
        }
        __syncthreads();                     // writes visible before next consume
    }

    // ---- store partials: C/D layout col = l15 (within d-block), row = lg*4+i
    float* pp = pws + (size_t)h * NND * DIM;
#pragma unroll
    for (int i = 0; i < 4; ++i) {
        pp[(size_t)(R0 +      lg * 4 + i) * DIM + 16 * w + l15] = accL[i];
        pp[(size_t)(R0 + 16 + lg * 4 + i) * DIM + 16 * w + l15] = accH[i];
    }
}

// Kernel 3: sum 4 k-quarter partials + fused epilogue. 1 row per wave.
__global__ __launch_bounds__(256) void k_fin(
    const float* __restrict__ pws, float* __restrict__ out)
{
    const int tid  = threadIdx.x;
    const int lane = tid & 63;
    const int wave = tid >> 6;
    const int row  = blockIdx.x * 4 + wave;
    const size_t base = (size_t)row * DIM + lane;
    const size_t S = (size_t)NND * DIM;
    float hv = (pws[base] + pws[S + base]) + (pws[2 * S + base] + pws[3 * S + base]);
    out[base] = epilogue_chain(hv, lane);
}

extern "C" void kernel_launch(void* const* d_in, const int* in_sizes, int n_in,
                              void* d_out, int out_size, void* d_ws, size_t ws_size,
                              hipStream_t stream)
{
    const float* x      = (const float*)d_in[0];
    const float* adj    = (const float*)d_in[1];
    const float* weight = (const float*)d_in[2];
    const float* bias   = (const float*)d_in[3];
    float* out = (float*)d_out;
    __bf16* l2bf = (__bf16*)d_ws;                          // 64 x PB bf16 = 1.33 MB
    float*  pws  = (float*)((char*)d_ws + 0x180000);       // 4 x 2 MB partials

    k_prep<<<2048, 256, 0, stream>>>(x, weight, bias, l2bf);
    k_mm<<<1024, 256, 0, stream>>>(adj, l2bf, pws);
    k_fin<<<2048, 256, 0, stream>>>(pws, out);
}